// Round 2
// baseline (128.424 us; speedup 1.0000x reference)
//
#include <hip/hip_runtime.h>
#include <math.h>

// ---------------------------------------------------------------------------
// out[b] = <Z0> of: [CNOT(1,0)·CNOT(0,1)·(Rot_l0 ⊗ Rot_l1)]^3 applied to
//          (RX(x0)|0>) ⊗ (RX(x1)|0>).
// Collapsed: out = r^T K r with r=(c0c1,c0s1,s0c1,s0s1), ci=cos(xi/2).
// Double-angle identities collapse further to a 3x3 bilinear form:
//   out = (1, cos x0, sin x0) · G · (1, cos x1, sin x1)^T
// G (9 floats) depends only on q_weights -> built once per block by lane 0
// into LDS (all blocks co-resident, builds overlap; ~2 us wall total).
// Sanity: weights=0 => G[1][0]=1 only => out = cos x0 (exact <Z0> of RX). ✓
// ---------------------------------------------------------------------------

struct c32 { float re, im; };
__device__ __forceinline__ c32 cmul(c32 a, c32 b) { return { a.re*b.re - a.im*b.im, a.re*b.im + a.im*b.re }; }
__device__ __forceinline__ c32 cconj(c32 a) { return { a.re, -a.im }; }

__device__ void build_G(const float* __restrict__ w, float* __restrict__ Gs)
{
    c32 M[4][4];
    #pragma unroll
    for (int i = 0; i < 4; ++i)
        #pragma unroll
        for (int j = 0; j < 4; ++j)
            M[i][j] = { (i == j) ? 1.f : 0.f, 0.f };

    for (int l = 0; l < 3; ++l) {
        c32 U[2][2][2]; // [wire][row][col]
        for (int q = 0; q < 2; ++q) {
            float phi   = w[(l*2 + q)*3 + 0];
            float theta = w[(l*2 + q)*3 + 1];
            float omega = w[(l*2 + q)*3 + 2];
            float c = __cosf(theta * 0.5f);
            float s = __sinf(theta * 0.5f);
            float ap = -0.5f * (phi + omega);   // ep = exp(i*ap)
            float am =  0.5f * (phi - omega);   // em = exp(i*am)
            c32 ep = { __cosf(ap), __sinf(ap) };
            c32 em = { __cosf(am), __sinf(am) };
            U[q][0][0] = {  ep.re * c,  ep.im * c };
            U[q][0][1] = { -em.re * s, -em.im * s };
            U[q][1][0] = {  em.re * s, -em.im * s };  // conj(em)*s
            U[q][1][1] = {  ep.re * c, -ep.im * c };  // conj(ep)*c
        }
        // A = kron(U0, U1)
        c32 A[4][4];
        for (int j = 0; j < 2; ++j)
            for (int k = 0; k < 2; ++k)
                for (int jp = 0; jp < 2; ++jp)
                    for (int kp = 0; kp < 2; ++kp)
                        A[2*j + k][2*jp + kp] = cmul(U[0][j][jp], U[1][k][kp]);
        // CNOT(0,1): swap rows 2,3.  CNOT(1,0): swap rows 1,3.
        for (int col = 0; col < 4; ++col) { c32 t = A[2][col]; A[2][col] = A[3][col]; A[3][col] = t; }
        for (int col = 0; col < 4; ++col) { c32 t = A[1][col]; A[1][col] = A[3][col]; A[3][col] = t; }
        // M = A * M
        c32 NM[4][4];
        for (int i = 0; i < 4; ++i)
            for (int j = 0; j < 4; ++j) {
                c32 acc = {0.f, 0.f};
                for (int k = 0; k < 4; ++k) { c32 t = cmul(A[i][k], M[k][j]); acc.re += t.re; acc.im += t.im; }
                NM[i][j] = acc;
            }
        for (int i = 0; i < 4; ++i)
            for (int j = 0; j < 4; ++j) M[i][j] = NM[i][j];
    }

    // H = M^dag D M, D = diag(1,1,-1,-1)
    const float Dv[4] = {1.f, 1.f, -1.f, -1.f};
    c32 H[4][4];
    for (int a = 0; a < 4; ++a)
        for (int b = 0; b < 4; ++b) {
            c32 acc = {0.f, 0.f};
            for (int c = 0; c < 4; ++c) {
                c32 t = cmul(cconj(M[c][a]), M[c][b]);
                acc.re += Dv[c] * t.re;
                acc.im += Dv[c] * t.im;
            }
            H[a][b] = acc;
        }

    // phi = (1, -i, -i, -1); K_ab = Re(conj(phi_a) * phi_b * H_ab)
    const c32 ph[4] = { {1.f,0.f}, {0.f,-1.f}, {0.f,-1.f}, {-1.f,0.f} };
    float K[16];
    for (int a = 0; a < 4; ++a)
        for (int b = 0; b < 4; ++b) {
            c32 f = cmul(cconj(ph[a]), ph[b]);
            K[a*4 + b] = f.re * H[a][b].re - f.im * H[a][b].im;
        }

    // G[p][q] = sum_{i,k,j,l} K[(2i+j)*4 + (2k+l)] * P[i][k][p] * P[j][l][q]
    // where u_i u_k over basis (1, cosx, sinx):
    //   P[0][0]=(.5,.5,0)  P[0][1]=P[1][0]=(0,0,.5)  P[1][1]=(.5,-.5,0)
    const float P[2][2][3] = { { {0.5f, 0.5f, 0.f}, {0.f, 0.f, 0.5f} },
                               { {0.f,  0.f, 0.5f}, {0.5f,-0.5f, 0.f} } };
    for (int p = 0; p < 3; ++p)
        for (int q = 0; q < 3; ++q) {
            float g = 0.f;
            for (int i = 0; i < 2; ++i)
                for (int k = 0; k < 2; ++k)
                    for (int j = 0; j < 2; ++j)
                        for (int l = 0; l < 2; ++l)
                            g += K[(2*i + j)*4 + (2*k + l)] * P[i][k][p] * P[j][l][q];
            Gs[p*3 + q] = g;
        }
}

__global__ __launch_bounds__(256, 4) void qfused(const float* __restrict__ x,
                                                 const float* __restrict__ w,
                                                 float* __restrict__ out, int B)
{
    __shared__ float Gs[9];
    if (threadIdx.x == 0) build_G(w, Gs);
    __syncthreads();

    const float G0 = Gs[0], G1 = Gs[1], G2 = Gs[2];
    const float G3 = Gs[3], G4 = Gs[4], G5 = Gs[5];
    const float G6 = Gs[6], G7 = Gs[7], G8 = Gs[8];

    const long long nq = B >> 2;                       // float4 outputs
    const long long stride = (long long)gridDim.x * blockDim.x;
    const float4* xv = (const float4*)x;
    float4* ov = (float4*)out;

    for (long long i = (long long)blockIdx.x * blockDim.x + threadIdx.x; i < nq; i += stride) {
        float4 a = xv[2*i];
        float4 b = xv[2*i + 1];
        float x0[4] = {a.x, a.z, b.x, b.z};
        float x1[4] = {a.y, a.w, b.y, b.w};
        float res[4];
        #pragma unroll
        for (int e = 0; e < 4; ++e) {
            float C0 = __cosf(x0[e]), S0 = __sinf(x0[e]);
            float C1 = __cosf(x1[e]), S1 = __sinf(x1[e]);
            float t0 = G0 + G1*C1 + G2*S1;
            float t1 = G3 + G4*C1 + G5*S1;
            float t2 = G6 + G7*C1 + G8*S1;
            res[e] = t0 + C0*t1 + S0*t2;
        }
        ov[i] = make_float4(res[0], res[1], res[2], res[3]);
    }

    // tail (B % 4 != 0) — handled by one thread
    if (blockIdx.x == 0 && threadIdx.x == 0) {
        for (long long i = nq*4; i < B; ++i) {
            float C0 = __cosf(x[2*i]),     S0 = __sinf(x[2*i]);
            float C1 = __cosf(x[2*i + 1]), S1 = __sinf(x[2*i + 1]);
            float t0 = G0 + G1*C1 + G2*S1;
            float t1 = G3 + G4*C1 + G5*S1;
            float t2 = G6 + G7*C1 + G8*S1;
            out[i] = t0 + C0*t1 + S0*t2;
        }
    }
}

extern "C" void kernel_launch(void* const* d_in, const int* in_sizes, int n_in,
                              void* d_out, int out_size, void* d_ws, size_t ws_size,
                              hipStream_t stream)
{
    const float* x = (const float*)d_in[0];      // [B, 2]
    const float* w = (const float*)d_in[1];      // [3, 2, 3]
    float* out = (float*)d_out;                  // [B]
    const int B = in_sizes[0] / 2;

    const int block = 256;
    const int grid  = 1024;                      // 4 blocks/CU, all co-resident
    qfused<<<grid, block, 0, stream>>>(x, w, out, B);
}

// Round 3
// 90.011 us; speedup vs baseline: 1.4268x; 1.4268x over previous
//
#include <hip/hip_runtime.h>
#include <math.h>

// ---------------------------------------------------------------------------
// out[b] = <Z0> of: [CNOT(1,0)·CNOT(0,1)·(Rot_l0 ⊗ Rot_l1)]^3 applied to
//          (RX(x0)|0>) ⊗ (RX(x1)|0>).
// Collapsed analytically to a 3x3 bilinear form:
//   out = (1, cos x0, sin x0) · G · (1, cos x1, sin x1)^T
// G (9 floats) depends only on q_weights. Two kernels:
//   build_G: 1 block, lane 0, full register budget (NO launch_bounds cap —
//            R2 showed a 64-VGPR cap makes this spill to scratch, ~45 us).
//   qexp:    pure streaming map, 8 elems/thread, exact grid.
// ---------------------------------------------------------------------------

struct c32 { float re, im; };
__device__ __forceinline__ c32 cmul(c32 a, c32 b) { return { a.re*b.re - a.im*b.im, a.re*b.im + a.im*b.re }; }
__device__ __forceinline__ c32 cconj(c32 a) { return { a.re, -a.im }; }

__global__ void build_G(const float* __restrict__ w, float* __restrict__ Gs)
{
    if (threadIdx.x != 0 || blockIdx.x != 0) return;

    c32 M[4][4];
    #pragma unroll
    for (int i = 0; i < 4; ++i)
        #pragma unroll
        for (int j = 0; j < 4; ++j)
            M[i][j] = { (i == j) ? 1.f : 0.f, 0.f };

    for (int l = 0; l < 3; ++l) {
        c32 U[2][2][2]; // [wire][row][col]
        for (int q = 0; q < 2; ++q) {
            float phi   = w[(l*2 + q)*3 + 0];
            float theta = w[(l*2 + q)*3 + 1];
            float omega = w[(l*2 + q)*3 + 2];
            float c = __cosf(theta * 0.5f);
            float s = __sinf(theta * 0.5f);
            float ap = -0.5f * (phi + omega);   // ep = exp(i*ap)
            float am =  0.5f * (phi - omega);   // em = exp(i*am)
            c32 ep = { __cosf(ap), __sinf(ap) };
            c32 em = { __cosf(am), __sinf(am) };
            U[q][0][0] = {  ep.re * c,  ep.im * c };
            U[q][0][1] = { -em.re * s, -em.im * s };
            U[q][1][0] = {  em.re * s, -em.im * s };  // conj(em)*s
            U[q][1][1] = {  ep.re * c, -ep.im * c };  // conj(ep)*c
        }
        // A = kron(U0, U1)
        c32 A[4][4];
        for (int j = 0; j < 2; ++j)
            for (int k = 0; k < 2; ++k)
                for (int jp = 0; jp < 2; ++jp)
                    for (int kp = 0; kp < 2; ++kp)
                        A[2*j + k][2*jp + kp] = cmul(U[0][j][jp], U[1][k][kp]);
        // CNOT(0,1): swap rows 2,3.  CNOT(1,0): swap rows 1,3.
        for (int col = 0; col < 4; ++col) { c32 t = A[2][col]; A[2][col] = A[3][col]; A[3][col] = t; }
        for (int col = 0; col < 4; ++col) { c32 t = A[1][col]; A[1][col] = A[3][col]; A[3][col] = t; }
        // M = A * M
        c32 NM[4][4];
        for (int i = 0; i < 4; ++i)
            for (int j = 0; j < 4; ++j) {
                c32 acc = {0.f, 0.f};
                for (int k = 0; k < 4; ++k) { c32 t = cmul(A[i][k], M[k][j]); acc.re += t.re; acc.im += t.im; }
                NM[i][j] = acc;
            }
        for (int i = 0; i < 4; ++i)
            for (int j = 0; j < 4; ++j) M[i][j] = NM[i][j];
    }

    // H = M^dag D M, D = diag(1,1,-1,-1)
    const float Dv[4] = {1.f, 1.f, -1.f, -1.f};
    c32 H[4][4];
    for (int a = 0; a < 4; ++a)
        for (int b = 0; b < 4; ++b) {
            c32 acc = {0.f, 0.f};
            for (int c = 0; c < 4; ++c) {
                c32 t = cmul(cconj(M[c][a]), M[c][b]);
                acc.re += Dv[c] * t.re;
                acc.im += Dv[c] * t.im;
            }
            H[a][b] = acc;
        }

    // phi = (1, -i, -i, -1); K_ab = Re(conj(phi_a) * phi_b * H_ab)
    const c32 ph[4] = { {1.f,0.f}, {0.f,-1.f}, {0.f,-1.f}, {-1.f,0.f} };
    float K[16];
    for (int a = 0; a < 4; ++a)
        for (int b = 0; b < 4; ++b) {
            c32 f = cmul(cconj(ph[a]), ph[b]);
            K[a*4 + b] = f.re * H[a][b].re - f.im * H[a][b].im;
        }

    // Collapse r^T K r (r=(c0c1,c0s1,s0c1,s0s1), half-angles) to the 3x3
    // bilinear form over basis (1, cos x, sin x):
    //   P[0][0]=(.5,.5,0)  P[0][1]=P[1][0]=(0,0,.5)  P[1][1]=(.5,-.5,0)
    const float P[2][2][3] = { { {0.5f, 0.5f, 0.f}, {0.f, 0.f, 0.5f} },
                               { {0.f,  0.f, 0.5f}, {0.5f,-0.5f, 0.f} } };
    for (int p = 0; p < 3; ++p)
        for (int q = 0; q < 3; ++q) {
            float g = 0.f;
            for (int i = 0; i < 2; ++i)
                for (int k = 0; k < 2; ++k)
                    for (int j = 0; j < 2; ++j)
                        for (int l = 0; l < 2; ++l)
                            g += K[(2*i + j)*4 + (2*k + l)] * P[i][k][p] * P[j][l][q];
            Gs[p*3 + q] = g;
        }
}

__global__ __launch_bounds__(256) void qexp(const float* __restrict__ x,
                                            const float* __restrict__ G9,
                                            float* __restrict__ out, int B)
{
    // 9 uniform-address loads -> scalar loads, L2-hit
    float G0 = G9[0], G1 = G9[1], G2 = G9[2];
    float G3 = G9[3], G4 = G9[4], G5 = G9[5];
    float G6 = G9[6], G7 = G9[7], G8 = G9[8];

    const long long t  = (long long)blockIdx.x * blockDim.x + threadIdx.x;
    const long long i0 = t * 8;                       // 8 elements per thread
    if (i0 >= B) return;

    if (i0 + 8 <= B) {
        const float4* xp = (const float4*)(x + 2*i0); // 64 B contiguous per lane
        float4 a = xp[0], b = xp[1], c = xp[2], d = xp[3];
        float x0[8] = {a.x, a.z, b.x, b.z, c.x, c.z, d.x, d.z};
        float x1[8] = {a.y, a.w, b.y, b.w, c.y, c.w, d.y, d.w};
        float res[8];
        #pragma unroll
        for (int e = 0; e < 8; ++e) {
            float C0 = __cosf(x0[e]), S0 = __sinf(x0[e]);
            float C1 = __cosf(x1[e]), S1 = __sinf(x1[e]);
            float t0 = G0 + G1*C1 + G2*S1;
            float t1 = G3 + G4*C1 + G5*S1;
            float t2 = G6 + G7*C1 + G8*S1;
            res[e] = t0 + C0*t1 + S0*t2;
        }
        float4* op = (float4*)(out + i0);
        op[0] = make_float4(res[0], res[1], res[2], res[3]);
        op[1] = make_float4(res[4], res[5], res[6], res[7]);
    } else {
        for (long long i = i0; i < B; ++i) {
            float C0 = __cosf(x[2*i]),     S0 = __sinf(x[2*i]);
            float C1 = __cosf(x[2*i + 1]), S1 = __sinf(x[2*i + 1]);
            float t0 = G0 + G1*C1 + G2*S1;
            float t1 = G3 + G4*C1 + G5*S1;
            float t2 = G6 + G7*C1 + G8*S1;
            out[i] = t0 + C0*t1 + S0*t2;
        }
    }
}

extern "C" void kernel_launch(void* const* d_in, const int* in_sizes, int n_in,
                              void* d_out, int out_size, void* d_ws, size_t ws_size,
                              hipStream_t stream)
{
    const float* x = (const float*)d_in[0];      // [B, 2]
    const float* w = (const float*)d_in[1];      // [3, 2, 3]
    float* out = (float*)d_out;                  // [B]
    float* G   = (float*)d_ws;                   // 9 floats scratch

    const int B = in_sizes[0] / 2;

    build_G<<<1, 64, 0, stream>>>(w, G);

    const long long n_threads = ((long long)B + 7) / 8;
    const int block = 256;
    const int grid  = (int)((n_threads + block - 1) / block);
    qexp<<<grid, block, 0, stream>>>(x, G, out, B);
}